// Round 1
// baseline (212.434 us; speedup 1.0000x reference)
//
#include <hip/hip_runtime.h>

#define SEQ_T 2048
#define HDIM  128
#define NB    16

typedef __attribute__((ext_vector_type(8))) short short8;      // 8 bf16 (4 VGPRs)
typedef __attribute__((ext_vector_type(4))) float float4v;
typedef __attribute__((ext_vector_type(4))) unsigned int uint4v;

// round-half-up fp32 -> bf16 (2 VALU ops), pack pair into one u32
__device__ __forceinline__ unsigned int bfpack2(float a, float b) {
  unsigned int ua = __builtin_bit_cast(unsigned int, a);
  unsigned int ub = __builtin_bit_cast(unsigned int, b);
  return ((ua + 0x8000u) >> 16) | ((ub + 0x8000u) & 0xFFFF0000u);
}
__device__ __forceinline__ unsigned short f2bf(float a) {
  unsigned int ua = __builtin_bit_cast(unsigned int, a);
  return (unsigned short)((ua + 0x8000u) >> 16);
}

// x layout: [B, T, 384] with k = [0,128), q = [128,256), v = [256,384)
__global__ __launch_bounds__(256) void attn_causal_kernel(const float* __restrict__ x,
                                                          float* __restrict__ out) {
  const int b    = blockIdx.y;
  const int qblk = (int)gridDim.x - 1 - (int)blockIdx.x;  // biggest-work blocks dispatch first
  const int qb0  = qblk << 6;                             // 64 q-rows per block
  const int tid  = threadIdx.x;
  const int wave = tid >> 6;
  const int lane = tid & 63;
  const int low  = lane & 15;
  const int quad = lane >> 4;
  const int q0   = qb0 + (wave << 4);                     // 16 q-rows per wave

  // K: row-major bf16, row stride 136 (pad 8 -> b128 reads conflict-free)
  __shared__ unsigned short Ks[32 * 136];
  // V: transposed (d-major) bf16, row stride 40, 16B-block swizzle pb=(h+(d>>3))&3
  __shared__ unsigned short Vt[128 * 40];
  // P: per-wave C-layout -> A-layout LDS round trip (m120 pattern)
  __shared__ unsigned short Ps[4][16 * 40];

  const float* xb = x + (size_t)b * (SEQ_T * 3 * HDIM);

  // ---- Q fragments (A-operand: A[m=lane&15][k=quad*8+j]), kept in regs all loop ----
  short8 qa[4];
  {
    const float* qrow = xb + (size_t)(q0 + low) * 384 + 128;
    for (int kc = 0; kc < 4; ++kc) {
      float4v f0 = *(const float4v*)(qrow + kc * 32 + quad * 8);
      float4v f1 = *(const float4v*)(qrow + kc * 32 + quad * 8 + 4);
      uint4v u = { bfpack2(f0[0], f0[1]), bfpack2(f0[2], f0[3]),
                   bfpack2(f1[0], f1[1]), bfpack2(f1[2], f1[3]) };
      qa[kc] = __builtin_bit_cast(short8, u);
    }
  }

  float4v accv[8];
  for (int i = 0; i < 8; ++i) accv[i] = (float4v){0.f, 0.f, 0.f, 0.f};
  float m_i[4] = {-1e30f, -1e30f, -1e30f, -1e30f};
  float l_i[4] = {0.f, 0.f, 0.f, 0.f};

  const int ntiles = (qb0 + 64) >> 5;   // block-uniform kv-tile count (causal)
  for (int ti = 0; ti < ntiles; ++ti) {
    const int c0 = ti << 5;
    __syncthreads();  // protect LDS from previous iteration's readers

    // ---- stage K tile (32 x 128) fp32->bf16, coalesced float4 loads, b64 LDS writes ----
    for (int i = 0; i < 4; ++i) {
      int f   = tid + (i << 8);
      int row = f >> 5;
      int c4  = (f & 31) << 2;
      float4v kf = *(const float4v*)(xb + (size_t)(c0 + row) * 384 + c4);
      *(uint2*)&Ks[row * 136 + c4] =
          make_uint2(bfpack2(kf[0], kf[1]), bfpack2(kf[2], kf[3]));
    }
    // ---- stage V tile transposed: thread owns a 4kv x 4d block (in-thread transpose) ----
    {
      int kb = tid >> 5;   // kv block: kv = 4*kb + jj
      int db = tid & 31;   // d  block: d  = 4*db + j
      const float* vbase = xb + (size_t)(c0 + 4 * kb) * 384 + 256 + 4 * db;
      float4v v0 = *(const float4v*)(vbase);
      float4v v1 = *(const float4v*)(vbase + 384);
      float4v v2 = *(const float4v*)(vbase + 768);
      float4v v3 = *(const float4v*)(vbase + 1152);
      for (int j = 0; j < 4; ++j) {
        int d  = 4 * db + j;
        int pb = ((kb >> 1) + (d >> 3)) & 3;   // swizzled 16B block
        *(uint2*)&Vt[d * 40 + pb * 8 + (kb & 1) * 4] =
            make_uint2(bfpack2(v0[j], v1[j]), bfpack2(v2[j], v3[j]));
      }
    }
    __syncthreads();

    if (c0 <= q0 + 15) {   // wave-uniform causal tile skip
      // ---- S = Q K^T : two 16-col tiles, K-dim 128 = 4 mfma steps each ----
      float4v s0 = {0.f,0.f,0.f,0.f}, s1 = {0.f,0.f,0.f,0.f};
      for (int kc = 0; kc < 4; ++kc) {
        short8 kf0 = *(const short8*)&Ks[low * 136 + kc * 32 + quad * 8];
        short8 kf1 = *(const short8*)&Ks[(16 + low) * 136 + kc * 32 + quad * 8];
        s0 = __builtin_amdgcn_mfma_f32_16x16x32_bf16(qa[kc], kf0, s0, 0, 0, 0);
        s1 = __builtin_amdgcn_mfma_f32_16x16x32_bf16(qa[kc], kf1, s1, 0, 0, 0);
      }
      // ---- scale + causal mask (C-layout: col = lane&15, row = quad*4+reg) ----
      const float scale = 0.08838834764831845f;   // 128^-0.5
      if (c0 + 31 > q0) {
        for (int r = 0; r < 4; ++r) {
          int qrow = q0 + quad * 4 + r;
          s0[r] = (c0 + low      <= qrow) ? s0[r] * scale : -1e30f;
          s1[r] = (c0 + 16 + low <= qrow) ? s1[r] * scale : -1e30f;
        }
      } else {
        for (int r = 0; r < 4; ++r) { s0[r] *= scale; s1[r] *= scale; }
      }
      // ---- online softmax (fp32): row max over 16 cols via shfl_xor ----
      float rmax[4], alpha[4];
      for (int r = 0; r < 4; ++r) rmax[r] = fmaxf(s0[r], s1[r]);
      for (int off = 1; off < 16; off <<= 1)
        for (int r = 0; r < 4; ++r)
          rmax[r] = fmaxf(rmax[r], __shfl_xor(rmax[r], off, 64));
      for (int r = 0; r < 4; ++r) {
        float mn = fmaxf(m_i[r], rmax[r]);
        alpha[r] = __expf(m_i[r] - mn);
        m_i[r]   = mn;
      }
      for (int r = 0; r < 4; ++r) {
        s0[r] = __expf(s0[r] - m_i[r]);   // masked: exp(-1e30 - m) = 0
        s1[r] = __expf(s1[r] - m_i[r]);
      }
      float rs[4];
      for (int r = 0; r < 4; ++r) rs[r] = s0[r] + s1[r];
      for (int off = 1; off < 16; off <<= 1)
        for (int r = 0; r < 4; ++r)
          rs[r] += __shfl_xor(rs[r], off, 64);
      for (int r = 0; r < 4; ++r) l_i[r] = l_i[r] * alpha[r] + rs[r];
      for (int nt = 0; nt < 8; ++nt)
        for (int r = 0; r < 4; ++r) accv[nt][r] *= alpha[r];

      // ---- P: C-layout -> LDS -> A-layout ----
      unsigned short* pw = Ps[wave];
      for (int r = 0; r < 4; ++r) {
        int row = quad * 4 + r;
        pw[row * 40 + low]      = f2bf(s0[r]);
        pw[row * 40 + 16 + low] = f2bf(s1[r]);
      }
      short8 pa = *(const short8*)&pw[low * 40 + quad * 8];

      // ---- O += P V : 8 d-tiles, single K=32 mfma each ----
      for (int nt = 0; nt < 8; ++nt) {
        int d  = nt * 16 + low;
        int pb = (quad + (d >> 3)) & 3;
        short8 vf = *(const short8*)&Vt[d * 40 + pb * 8];
        accv[nt] = __builtin_amdgcn_mfma_f32_16x16x32_bf16(pa, vf, accv[nt], 0, 0, 0);
      }
    }
  }

  // ---- epilogue: O / l ----
  float inv[4];
  for (int r = 0; r < 4; ++r) inv[r] = 1.f / l_i[r];
  float* ob = out + ((size_t)b * SEQ_T + q0) * HDIM;
  for (int nt = 0; nt < 8; ++nt)
    for (int r = 0; r < 4; ++r)
      ob[(size_t)(quad * 4 + r) * HDIM + nt * 16 + low] = accv[nt][r] * inv[r];
}

extern "C" void kernel_launch(void* const* d_in, const int* in_sizes, int n_in,
                              void* d_out, int out_size, void* d_ws, size_t ws_size,
                              hipStream_t stream) {
  const float* x = (const float*)d_in[0];
  float* out = (float*)d_out;
  dim3 grid(SEQ_T / 64, NB);
  dim3 block(256);
  hipLaunchKernelGGL(attn_causal_kernel, grid, block, 0, stream, x, out);
}